// Round 1
// baseline (1744.746 us; speedup 1.0000x reference)
//
#include <hip/hip_runtime.h>

#define NB 4
#define NC 64
#define NG 48
#define NV (48*48*48)
#define NA 64
#define NE 128

// ---------------- kernel 1: vmat[b][a][c] = mol_embed @ v_w^T + v_b ----------
__global__ void k_vmat(const float* __restrict__ me, const float* __restrict__ vw,
                       const float* __restrict__ vb, float* __restrict__ vmat) {
  int b = blockIdx.x, t = threadIdx.x;
  for (int idx = t; idx < NA * NC; idx += 256) {
    int a = idx >> 6, c = idx & 63;
    const float* mp = me + (b * NA + a) * NE;
    const float* wp = vw + c * NE;
    float acc = vb[c];
#pragma unroll 4
    for (int e = 0; e < NE; ++e) acc += mp[e] * wp[e];
    vmat[b * NA * NC + idx] = acc;
  }
}

// ------------- kernel 1b: transpose conv weights to [ci][off][co] ------------
__global__ void k_wt(const float* __restrict__ cw, float* __restrict__ wtg) {
  int idx = blockIdx.x * 256 + threadIdx.x;
  if (idx >= NC * NC * 27) return;
  int ci = idx / (27 * 64);
  int r = idx % (27 * 64);
  int off = r >> 6, co = r & 63;
  wtg[idx] = cw[(co * 64 + ci) * 27 + off];
}

// -------- kernel 2: attention + att@v + out-projection, h -> ws --------------
// block: 64 voxels (v0..v0+63) of batch b.  256 threads.
// LDS layout (floats):
//   vm   @0      4096   [a][c]          (phases A-C)   } overlapped by
//   att  @4096   64*68  [v][a]          (phases B-C)   } owt (8704) in D-E
//   vatt @8704   64*68  [v][c]
//   xv   @13056  64*68  [v][c]   (reused as stg [o][68] for writeback)
//   ps   @17408  192
//   sinv @17600  64
__global__ __launch_bounds__(256) void k_attn(
    const float* __restrict__ x, const float* __restrict__ pos,
    const float* __restrict__ origin, const float* __restrict__ lattice,
    const int* __restrict__ bnodes, const float* __restrict__ ow,
    const float* __restrict__ ob, const float* __restrict__ vmat,
    float* __restrict__ hout) {
  __shared__ float sm[17664];
  float* vm = sm;
  float* att = sm + 4096;
  float* owt = sm;           // [k][68] -> o   (reuses vm+att region)
  float* vatt = sm + 8704;
  float* xv = sm + 13056;
  float* ps = sm + 17408;
  float* sinv = sm + 17600;
  int t = threadIdx.x;
  int b = blockIdx.y;
  int v0 = blockIdx.x * 64;

  // phase A: stage vmat + pos
  for (int idx = t; idx < 4096; idx += 256) vm[idx] = vmat[b * 4096 + idx];
  if (t < 192) ps[t] = pos[b * 192 + t];
  __syncthreads();

  // phase B: wave0 = attention; waves 1-3 = stage xv (x slice, [v][c])
  if (t < 64) {
    int v = v0 + t;
    int ix = v / 2304;
    int rem = v - ix * 2304;
    int iy = rem / 48;
    int iz = rem - iy * 48;
    float gx = origin[b * 3 + 0] + lattice[b * 9 + 0] * (ix * (1.0f / 47.0f));
    float gy = origin[b * 3 + 1] + lattice[b * 9 + 4] * (iy * (1.0f / 47.0f));
    float gz = origin[b * 3 + 2] + lattice[b * 9 + 8] * (iz * (1.0f / 47.0f));
    int na = bnodes[b];
    float wmax = -3.0e38f;
    for (int a = 0; a < 64; ++a) {
      float dx = gx - ps[a * 3 + 0];
      float dy = gy - ps[a * 3 + 1];
      float dz = gz - ps[a * 3 + 2];
      float d = sqrtf(fmaxf(dx * dx + dy * dy + dz * dz, 1e-12f));
      att[t * 68 + a] = -d;
      if (a < na) wmax = fmaxf(wmax, -d);
    }
    float s = 0.f;
    for (int a = 0; a < 64; ++a) {
      float e = (a < na) ? __expf(att[t * 68 + a] - wmax) : 0.f;
      att[t * 68 + a] = e;
      s += e;
    }
    sinv[t] = 1.0f / s;   // normalization folded into step2
  } else {
    for (int idx = t - 64; idx < 4096; idx += 192) {
      int c = idx >> 6, vl = idx & 63;
      xv[vl * 68 + c] = x[(b * 64 + c) * NV + v0 + vl];
    }
  }
  __syncthreads();

  int vb = t & 15;         // thread's v's: vb, vb+16, vb+32, vb+48 (2-way-max LDS)
  int ct = (t >> 4) * 4;   // 4 contiguous c (or o) columns

  // phase C: vatt = softmax(att) @ vm
  {
    float acc[4][4];
#pragma unroll
    for (int i = 0; i < 4; ++i)
#pragma unroll
      for (int j = 0; j < 4; ++j) acc[i][j] = 0.f;
    for (int a0 = 0; a0 < 64; a0 += 4) {
      float at4[4][4], vm4[4][4];
#pragma unroll
      for (int vl = 0; vl < 4; ++vl) {
        float4 tmp = *(const float4*)&att[(vb + 16 * vl) * 68 + a0];
        at4[vl][0] = tmp.x; at4[vl][1] = tmp.y; at4[vl][2] = tmp.z; at4[vl][3] = tmp.w;
      }
#pragma unroll
      for (int kk = 0; kk < 4; ++kk) {
        float4 tmp = *(const float4*)&vm[(a0 + kk) * 64 + ct];
        vm4[kk][0] = tmp.x; vm4[kk][1] = tmp.y; vm4[kk][2] = tmp.z; vm4[kk][3] = tmp.w;
      }
#pragma unroll
      for (int kk = 0; kk < 4; ++kk)
#pragma unroll
        for (int vl = 0; vl < 4; ++vl)
#pragma unroll
          for (int j = 0; j < 4; ++j) acc[vl][j] += at4[vl][kk] * vm4[kk][j];
    }
#pragma unroll
    for (int vl = 0; vl < 4; ++vl) {
      float inv = sinv[vb + 16 * vl];
      float4 o4 = {acc[vl][0] * inv, acc[vl][1] * inv, acc[vl][2] * inv, acc[vl][3] * inv};
      *(float4*)&vatt[(vb + 16 * vl) * 68 + ct] = o4;
    }
  }
  __syncthreads();

  // phase D: stage out_w transposed [k][o]
  for (int idx = t; idx < 8192; idx += 256) {
    int o = idx >> 7, k = idx & 127;
    owt[k * 68 + o] = ow[idx];
  }
  __syncthreads();

  // phase E: h = relu([xv, vatt] @ out_w^T + out_b)
  float acc[4][4];
  {
    float bj[4];
#pragma unroll
    for (int j = 0; j < 4; ++j) bj[j] = ob[ct + j];
#pragma unroll
    for (int vl = 0; vl < 4; ++vl)
#pragma unroll
      for (int j = 0; j < 4; ++j) acc[vl][j] = bj[j];
    for (int k0 = 0; k0 < 128; k0 += 4) {
      const float* src = (k0 < 64) ? xv : vatt;
      int kk0 = (k0 < 64) ? k0 : (k0 - 64);
      float hv[4][4], w4[4][4];
#pragma unroll
      for (int vl = 0; vl < 4; ++vl) {
        float4 tmp = *(const float4*)&src[(vb + 16 * vl) * 68 + kk0];
        hv[vl][0] = tmp.x; hv[vl][1] = tmp.y; hv[vl][2] = tmp.z; hv[vl][3] = tmp.w;
      }
#pragma unroll
      for (int kk = 0; kk < 4; ++kk) {
        float4 tmp = *(const float4*)&owt[(k0 + kk) * 68 + ct];
        w4[kk][0] = tmp.x; w4[kk][1] = tmp.y; w4[kk][2] = tmp.z; w4[kk][3] = tmp.w;
      }
#pragma unroll
      for (int kk = 0; kk < 4; ++kk)
#pragma unroll
        for (int vl = 0; vl < 4; ++vl)
#pragma unroll
          for (int j = 0; j < 4; ++j) acc[vl][j] += hv[vl][kk] * w4[kk][j];
    }
  }
  __syncthreads();
  // phase F: stage relu(h) into stg[o][v] (reuse xv region) and write coalesced
  float* stg = xv;
#pragma unroll
  for (int j = 0; j < 4; ++j)
#pragma unroll
    for (int vl = 0; vl < 4; ++vl)
      stg[(ct + j) * 68 + vb + 16 * vl] = fmaxf(acc[vl][j], 0.f);
  __syncthreads();
  for (int idx = t; idx < 4096; idx += 256) {
    int o = idx >> 6, vl = idx & 63;
    hout[(b * 64 + o) * NV + v0 + vl] = stg[o * 68 + vl];
  }
}

// ------------- kernel 3: wrap-conv 3x3x3 + bias + relu + residual ------------
// grid (48 x, 12 ygroups, 4 b); block 256: g=t>>6 (y), co4=(t&63)>>2, zq=t&3
// thread register tile: 4 co x 12 z.
__global__ __launch_bounds__(256) void k_conv(
    const float* __restrict__ h, const float* __restrict__ wtg,
    const float* __restrict__ cb, const float* __restrict__ x,
    float* __restrict__ out) {
  __shared__ float wt[6912];  // [ci4][27][64co]
  __shared__ float hs[3744];  // [ci4][dx3][dy6][52]  (z halo at 0 and 49)
  int t = threadIdx.x;
  int ix = blockIdx.x, iy0 = blockIdx.y * 4, b = blockIdx.z;
  int g = t >> 6, tt = t & 63;
  int co4 = tt >> 2, zq = tt & 3;
  float acc[4][12];
#pragma unroll
  for (int cc = 0; cc < 4; ++cc)
#pragma unroll
    for (int j = 0; j < 12; ++j) acc[cc][j] = 0.f;

  for (int ci0 = 0; ci0 < 64; ci0 += 4) {
    __syncthreads();
    for (int idx = t; idx < 6912; idx += 256) wt[idx] = wtg[ci0 * 27 * 64 + idx];
    for (int idx = t; idx < 3600; idx += 256) {
      int row = idx / 50, zz = idx - row * 50;
      int ci_ = row / 18, r2 = row - ci_ * 18;
      int dx = r2 / 6, dyy = r2 - dx * 6;
      int sx = ix + dx - 1;
      sx += (sx < 0) ? 48 : 0;
      sx -= (sx >= 48) ? 48 : 0;
      int sy = iy0 + dyy - 1;
      sy += (sy < 0) ? 48 : 0;
      sy -= (sy >= 48) ? 48 : 0;
      int sz = zz - 1;
      sz += (sz < 0) ? 48 : 0;
      sz -= (sz >= 48) ? 48 : 0;
      hs[row * 52 + zz] = h[((b * 64 + ci0 + ci_) * 2304 + sx * 48 + sy) * 48 + sz];
    }
    __syncthreads();
#pragma unroll
    for (int ci_ = 0; ci_ < 4; ++ci_) {
#pragma unroll
      for (int dx = 0; dx < 3; ++dx) {
#pragma unroll
        for (int dyr = 0; dyr < 3; ++dyr) {
          const float* hp = &hs[(ci_ * 18 + dx * 6 + g + dyr) * 52 + zq * 12];
          float hrow[14];
          {
            float4 h0 = *(const float4*)(hp);
            float4 h1 = *(const float4*)(hp + 4);
            float4 h2 = *(const float4*)(hp + 8);
            hrow[0] = h0.x; hrow[1] = h0.y; hrow[2] = h0.z; hrow[3] = h0.w;
            hrow[4] = h1.x; hrow[5] = h1.y; hrow[6] = h1.z; hrow[7] = h1.w;
            hrow[8] = h2.x; hrow[9] = h2.y; hrow[10] = h2.z; hrow[11] = h2.w;
            hrow[12] = hp[12]; hrow[13] = hp[13];
          }
#pragma unroll
          for (int dz = 0; dz < 3; ++dz) {
            float4 wv = *(const float4*)&wt[(ci_ * 27 + (dx * 3 + dyr) * 3 + dz) * 64 + co4 * 4];
#pragma unroll
            for (int j = 0; j < 12; ++j) {
              float hval = hrow[j + dz];
              acc[0][j] += wv.x * hval;
              acc[1][j] += wv.y * hval;
              acc[2][j] += wv.z * hval;
              acc[3][j] += wv.w * hval;
            }
          }
        }
      }
    }
  }
  // epilogue: bias + relu + residual
  int iy = iy0 + g;
#pragma unroll
  for (int cc = 0; cc < 4; ++cc) {
    int co = co4 * 4 + cc;
    float bias = cb[co];
    int base = ((b * 64 + co) * 2304 + ix * 48 + iy) * 48;
#pragma unroll
    for (int j = 0; j < 12; ++j) {
      int z = zq * 12 + j;
      out[base + z] = fmaxf(acc[cc][j] + bias, 0.f) + x[base + z];
    }
  }
}

extern "C" void kernel_launch(void* const* d_in, const int* in_sizes, int n_in,
                              void* d_out, int out_size, void* d_ws, size_t ws_size,
                              hipStream_t stream) {
  const float* x = (const float*)d_in[0];
  const float* me = (const float*)d_in[1];
  const float* pos = (const float*)d_in[2];
  const float* origin = (const float*)d_in[3];
  const float* lattice = (const float*)d_in[4];
  const int* bn = (const int*)d_in[5];
  const float* vw = (const float*)d_in[6];
  const float* vb = (const float*)d_in[7];
  const float* ow = (const float*)d_in[8];
  const float* ob = (const float*)d_in[9];
  const float* cw = (const float*)d_in[10];
  const float* cbias = (const float*)d_in[11];
  float* outp = (float*)d_out;

  float* vmat = (float*)d_ws;                       // 16384 floats
  float* h = vmat + NB * NA * NC;                   // 28311552 floats
  float* wtg = h + (size_t)NB * NC * NV;            // 110592 floats

  k_vmat<<<NB, 256, 0, stream>>>(me, vw, vb, vmat);
  k_wt<<<(NC * NC * 27 + 255) / 256, 256, 0, stream>>>(cw, wtg);
  k_attn<<<dim3(NV / 64, NB), 256, 0, stream>>>(x, pos, origin, lattice, bn, ow, ob, vmat, h);
  k_conv<<<dim3(48, 12, NB), 256, 0, stream>>>(h, wtg, cbias, x, outp);
}

// Round 2
// 592.345 us; speedup vs baseline: 2.9455x; 2.9455x over previous
//
#include <hip/hip_runtime.h>

#define NB 4
#define NC 64
#define NG 48
#define NV (48*48*48)
#define NA 64
#define NE 128

typedef __attribute__((ext_vector_type(8))) short short8;
typedef __attribute__((ext_vector_type(4))) float f32x4;

static __device__ __forceinline__ ushort f2bf(float f) {
  unsigned u = __float_as_uint(f);
  unsigned r = (u + 0x7FFF + ((u >> 16) & 1)) >> 16;
  return (ushort)r;
}

// ---------------- kernel 1: vmat[b][a][c] = mol_embed @ v_w^T + v_b ----------
__global__ void k_vmat(const float* __restrict__ me, const float* __restrict__ vw,
                       const float* __restrict__ vb, float* __restrict__ vmat) {
  int b = blockIdx.x, t = threadIdx.x;
  for (int idx = t; idx < NA * NC; idx += 256) {
    int a = idx >> 6, c = idx & 63;
    const float* mp = me + (b * NA + a) * NE;
    const float* wp = vw + c * NE;
    float acc = vb[c];
#pragma unroll 4
    for (int e = 0; e < NE; ++e) acc += mp[e] * wp[e];
    vmat[b * NA * NC + idx] = acc;
  }
}

// --------- kernel 1b: conv weights -> bf16 [off][co][ci] ---------------------
__global__ void k_wt(const float* __restrict__ cw, ushort* __restrict__ wbf) {
  int idx = blockIdx.x * 256 + threadIdx.x;
  if (idx >= 27 * 64 * 64) return;
  int off = idx >> 12, r = idx & 4095, co = r >> 6, ci = r & 63;
  wbf[idx] = f2bf(cw[(co * 64 + ci) * 27 + off]);
}

// -------- kernel 2: attention + att@v + out-projection, h(bf16) -> ws --------
__global__ __launch_bounds__(256) void k_attn(
    const float* __restrict__ x, const float* __restrict__ pos,
    const float* __restrict__ origin, const float* __restrict__ lattice,
    const int* __restrict__ bnodes, const float* __restrict__ ow,
    const float* __restrict__ ob, const float* __restrict__ vmat,
    ushort* __restrict__ hbf) {
  __shared__ float sm[17664];
  float* vm = sm;
  float* att = sm + 4096;
  float* owt = sm;           // [k][68] -> o   (reuses vm+att region)
  float* vatt = sm + 8704;
  float* xv = sm + 13056;
  float* ps = sm + 17408;
  float* sinv = sm + 17600;
  int t = threadIdx.x;
  int b = blockIdx.y;
  int v0 = blockIdx.x * 64;

  for (int idx = t; idx < 4096; idx += 256) vm[idx] = vmat[b * 4096 + idx];
  if (t < 192) ps[t] = pos[b * 192 + t];
  __syncthreads();

  if (t < 64) {
    int v = v0 + t;
    int ix = v / 2304;
    int rem = v - ix * 2304;
    int iy = rem / 48;
    int iz = rem - iy * 48;
    float gx = origin[b * 3 + 0] + lattice[b * 9 + 0] * (ix * (1.0f / 47.0f));
    float gy = origin[b * 3 + 1] + lattice[b * 9 + 4] * (iy * (1.0f / 47.0f));
    float gz = origin[b * 3 + 2] + lattice[b * 9 + 8] * (iz * (1.0f / 47.0f));
    int na = bnodes[b];
    float wmax = -3.0e38f;
    for (int a = 0; a < 64; ++a) {
      float dx = gx - ps[a * 3 + 0];
      float dy = gy - ps[a * 3 + 1];
      float dz = gz - ps[a * 3 + 2];
      float d = sqrtf(fmaxf(dx * dx + dy * dy + dz * dz, 1e-12f));
      att[t * 68 + a] = -d;
      if (a < na) wmax = fmaxf(wmax, -d);
    }
    float s = 0.f;
    for (int a = 0; a < 64; ++a) {
      float e = (a < na) ? __expf(att[t * 68 + a] - wmax) : 0.f;
      att[t * 68 + a] = e;
      s += e;
    }
    sinv[t] = 1.0f / s;
  } else {
    for (int idx = t - 64; idx < 4096; idx += 192) {
      int c = idx >> 6, vl = idx & 63;
      xv[vl * 68 + c] = x[(b * 64 + c) * NV + v0 + vl];
    }
  }
  __syncthreads();

  int vb = t & 15;
  int ct = (t >> 4) * 4;

  {
    float acc[4][4];
#pragma unroll
    for (int i = 0; i < 4; ++i)
#pragma unroll
      for (int j = 0; j < 4; ++j) acc[i][j] = 0.f;
    for (int a0 = 0; a0 < 64; a0 += 4) {
      float at4[4][4], vm4[4][4];
#pragma unroll
      for (int vl = 0; vl < 4; ++vl) {
        float4 tmp = *(const float4*)&att[(vb + 16 * vl) * 68 + a0];
        at4[vl][0] = tmp.x; at4[vl][1] = tmp.y; at4[vl][2] = tmp.z; at4[vl][3] = tmp.w;
      }
#pragma unroll
      for (int kk = 0; kk < 4; ++kk) {
        float4 tmp = *(const float4*)&vm[(a0 + kk) * 64 + ct];
        vm4[kk][0] = tmp.x; vm4[kk][1] = tmp.y; vm4[kk][2] = tmp.z; vm4[kk][3] = tmp.w;
      }
#pragma unroll
      for (int kk = 0; kk < 4; ++kk)
#pragma unroll
        for (int vl = 0; vl < 4; ++vl)
#pragma unroll
          for (int j = 0; j < 4; ++j) acc[vl][j] += at4[vl][kk] * vm4[kk][j];
    }
#pragma unroll
    for (int vl = 0; vl < 4; ++vl) {
      float inv = sinv[vb + 16 * vl];
      float4 o4 = {acc[vl][0] * inv, acc[vl][1] * inv, acc[vl][2] * inv, acc[vl][3] * inv};
      *(float4*)&vatt[(vb + 16 * vl) * 68 + ct] = o4;
    }
  }
  __syncthreads();

  for (int idx = t; idx < 8192; idx += 256) {
    int o = idx >> 7, k = idx & 127;
    owt[k * 68 + o] = ow[idx];
  }
  __syncthreads();

  float acc[4][4];
  {
    float bj[4];
#pragma unroll
    for (int j = 0; j < 4; ++j) bj[j] = ob[ct + j];
#pragma unroll
    for (int vl = 0; vl < 4; ++vl)
#pragma unroll
      for (int j = 0; j < 4; ++j) acc[vl][j] = bj[j];
    for (int k0 = 0; k0 < 128; k0 += 4) {
      const float* src = (k0 < 64) ? xv : vatt;
      int kk0 = (k0 < 64) ? k0 : (k0 - 64);
      float hv[4][4], w4[4][4];
#pragma unroll
      for (int vl = 0; vl < 4; ++vl) {
        float4 tmp = *(const float4*)&src[(vb + 16 * vl) * 68 + kk0];
        hv[vl][0] = tmp.x; hv[vl][1] = tmp.y; hv[vl][2] = tmp.z; hv[vl][3] = tmp.w;
      }
#pragma unroll
      for (int kk = 0; kk < 4; ++kk) {
        float4 tmp = *(const float4*)&owt[(k0 + kk) * 68 + ct];
        w4[kk][0] = tmp.x; w4[kk][1] = tmp.y; w4[kk][2] = tmp.z; w4[kk][3] = tmp.w;
      }
#pragma unroll
      for (int kk = 0; kk < 4; ++kk)
#pragma unroll
        for (int vl = 0; vl < 4; ++vl)
#pragma unroll
          for (int j = 0; j < 4; ++j) acc[vl][j] += hv[vl][kk] * w4[kk][j];
    }
  }
  __syncthreads();
  // stage relu(h) as bf16 [v][c] then copy contiguous (8 KB) to global
  ushort* stg16 = (ushort*)xv;
#pragma unroll
  for (int vl = 0; vl < 4; ++vl)
#pragma unroll
    for (int j = 0; j < 4; ++j)
      stg16[(vb + 16 * vl) * 64 + ct + j] = f2bf(fmaxf(acc[vl][j], 0.f));
  __syncthreads();
  char* dst = (char*)hbf + ((size_t)(b * NV + v0)) * 128;
  const char* srcb = (const char*)stg16;
  for (int c = t; c < 512; c += 256)
    *(uint4*)(dst + c * 16) = *(const uint4*)(srcb + c * 16);
}

// ------------- kernel 3: MFMA wrap-conv 3x3x3 + bias + relu + residual -------
// 256 thr / 4 waves; tile (2x,4y,16z)=128 vox x 64 co; halo 4x6x18 rows.
// LDS: halo 55296 B (slot^(row&7) swizzle) + W dbuf 2x8192 = 71680 B.
__global__ __launch_bounds__(256) void k_conv(
    const ushort* __restrict__ hbf, const ushort* __restrict__ wbf,
    const float* __restrict__ cb, const float* __restrict__ x,
    float* __restrict__ out) {
  __shared__ char sm[71680];
  char* wb0 = sm + 55296;
  char* wb1 = sm + 63488;
  int t = threadIdx.x;
  int lane = t & 63, wave = t >> 6;
  int lm = lane & 15, lg = lane >> 4;

  int bid = blockIdx.x;                       // 0..3455, XCD swizzle
  int sw = (bid & 7) * 432 + (bid >> 3);
  int b = sw / 864, tid = sw - b * 864;
  int xt = tid / 36, rem = tid - xt * 36, yt = rem / 3, zt = rem - yt * 3;
  int x0 = xt * 2, y0 = yt * 4, z0 = zt * 16;

  const char* hbase = (const char*)hbf + (size_t)b * NV * 128;

  // stage halo (432 rows x 128 B), swizzled slots
  for (int c = t; c < 3456; c += 256) {
    int r = c >> 3, j = c & 7;
    int hx = r / 108, rr = r - hx * 108, hy = rr / 18, hz = rr - hy * 18;
    int gx = x0 + hx - 1; gx += (gx < 0) ? 48 : 0; gx -= (gx >= 48) ? 48 : 0;
    int gy = y0 + hy - 1; gy += (gy < 0) ? 48 : 0; gy -= (gy >= 48) ? 48 : 0;
    int gz = z0 + hz - 1; gz += (gz < 0) ? 48 : 0; gz -= (gz >= 48) ? 48 : 0;
    uint4 v = *(const uint4*)(hbase + ((size_t)(gx * 2304 + gy * 48 + gz) * 128 + j * 16));
    *(uint4*)(sm + r * 128 + ((j ^ (r & 7)) * 16)) = v;
  }
  // stage W[0]
  {
    const char* ws = (const char*)wbf;
#pragma unroll
    for (int k = 0; k < 2; ++k) {
      int c = t + k * 256;
      int co = c >> 3, j = c & 7;
      uint4 v = *(const uint4*)(ws + c * 16);
      *(uint4*)(wb0 + co * 128 + ((j ^ (co & 7)) * 16)) = v;
    }
  }
  __syncthreads();

  f32x4 acc[2][4];
#pragma unroll
  for (int i = 0; i < 2; ++i)
#pragma unroll
    for (int j = 0; j < 4; ++j) acc[i][j] = (f32x4){0.f, 0.f, 0.f, 0.f};

  for (int off = 0; off < 27; ++off) {
    char* wcur = (off & 1) ? wb1 : wb0;
    char* wnxt = (off & 1) ? wb0 : wb1;
    uint4 wreg0, wreg1;
    bool pf = (off + 1 < 27);
    if (pf) {
      const char* ws = (const char*)wbf + (size_t)(off + 1) * 8192;
      wreg0 = *(const uint4*)(ws + t * 16);
      wreg1 = *(const uint4*)(ws + (t + 256) * 16);
    }
    int dx = off / 9, dyz = off - dx * 9, dy = dyz / 3, dz = dyz - dy * 3;
    int r_mt[2];
#pragma unroll
    for (int mt = 0; mt < 2; ++mt) {
      int q = wave * 2 + mt;
      int tx = q >> 2, ty = q & 3;
      r_mt[mt] = ((tx + dx) * 6 + (ty + dy)) * 18 + lm + dz;
    }
#pragma unroll
    for (int kc = 0; kc < 2; ++kc) {
      int s = kc * 4 + lg;
      short8 a[2], bb[4];
#pragma unroll
      for (int mt = 0; mt < 2; ++mt) {
        int r = r_mt[mt];
        a[mt] = *(const short8*)(sm + r * 128 + ((s ^ (r & 7)) * 16));
      }
#pragma unroll
      for (int nt = 0; nt < 4; ++nt) {
        int co = nt * 16 + lm;
        bb[nt] = *(const short8*)(wcur + co * 128 + ((s ^ (co & 7)) * 16));
      }
#pragma unroll
      for (int mt = 0; mt < 2; ++mt)
#pragma unroll
        for (int nt = 0; nt < 4; ++nt)
          acc[mt][nt] = __builtin_amdgcn_mfma_f32_16x16x32_bf16(a[mt], bb[nt], acc[mt][nt], 0, 0, 0);
    }
    if (pf) {
      int co0 = t >> 3, j0 = t & 7;
      *(uint4*)(wnxt + co0 * 128 + ((j0 ^ (co0 & 7)) * 16)) = wreg0;
      int c1 = t + 256, co1 = c1 >> 3, j1 = c1 & 7;
      *(uint4*)(wnxt + co1 * 128 + ((j1 ^ (co1 & 7)) * 16)) = wreg1;
    }
    __syncthreads();
  }

  // epilogue: transpose via LDS (reuses halo region), coalesced store
  float* ep = (float*)sm;   // [co][132]
#pragma unroll
  for (int mt = 0; mt < 2; ++mt)
#pragma unroll
    for (int nt = 0; nt < 4; ++nt) {
      int co = nt * 16 + lm;
      int vbase = wave * 32 + mt * 16 + lg * 4;
#pragma unroll
      for (int rg = 0; rg < 4; ++rg)
        ep[co * 132 + vbase + rg] = acc[mt][nt][rg];
    }
  __syncthreads();
  const float* xb = x + (size_t)b * NC * NV;
  float* ob = out + (size_t)b * NC * NV;
  for (int i = t; i < 2048; i += 256) {
    int co = i >> 5, vq = i & 31;
    float4 v = *(const float4*)&ep[co * 132 + vq * 4];
    int vloc = vq * 4;
    int q = vloc >> 4, tz = vloc & 15;
    int tx = q >> 2, ty = q & 3;
    size_t g = (size_t)co * NV + (x0 + tx) * 2304 + (y0 + ty) * 48 + (z0 + tz);
    float4 xr = *(const float4*)(xb + g);
    float bias = cb[co];
    float4 o;
    o.x = fmaxf(v.x + bias, 0.f) + xr.x;
    o.y = fmaxf(v.y + bias, 0.f) + xr.y;
    o.z = fmaxf(v.z + bias, 0.f) + xr.z;
    o.w = fmaxf(v.w + bias, 0.f) + xr.w;
    *(float4*)(ob + g) = o;
  }
}

extern "C" void kernel_launch(void* const* d_in, const int* in_sizes, int n_in,
                              void* d_out, int out_size, void* d_ws, size_t ws_size,
                              hipStream_t stream) {
  const float* x = (const float*)d_in[0];
  const float* me = (const float*)d_in[1];
  const float* pos = (const float*)d_in[2];
  const float* origin = (const float*)d_in[3];
  const float* lattice = (const float*)d_in[4];
  const int* bn = (const int*)d_in[5];
  const float* vw = (const float*)d_in[6];
  const float* vb = (const float*)d_in[7];
  const float* ow = (const float*)d_in[8];
  const float* ob = (const float*)d_in[9];
  const float* cw = (const float*)d_in[10];
  const float* cbias = (const float*)d_in[11];
  float* outp = (float*)d_out;

  float* vmat = (float*)d_ws;                               // 16384 f32 = 64 KB
  ushort* wbf = (ushort*)((char*)d_ws + 65536);             // 110592 bf16 = 216 KB
  ushort* hbf = (ushort*)((char*)d_ws + 65536 + 221184);    // 4*V*64 bf16 = 56.6 MB

  k_vmat<<<NB, 256, 0, stream>>>(me, vw, vb, vmat);
  k_wt<<<(27 * 64 * 64 + 255) / 256, 256, 0, stream>>>(cw, wbf);
  k_attn<<<dim3(NV / 64, NB), 256, 0, stream>>>(x, pos, origin, lattice, bn, ow, ob, vmat, hbf);
  k_conv<<<3456, 256, 0, stream>>>(hbf, wbf, cbias, x, outp);
}

// Round 3
// 247.181 us; speedup vs baseline: 7.0586x; 2.3964x over previous
//
#include <hip/hip_runtime.h>

#define NB 4
#define NC 64
#define NV (48*48*48)
#define NA 64
#define NE 128

typedef __attribute__((ext_vector_type(8))) short short8;
typedef __attribute__((ext_vector_type(4))) float f32x4;

static __device__ __forceinline__ ushort f2bf(float f) {
  unsigned u = __float_as_uint(f);
  unsigned r = (u + 0x7FFF + ((u >> 16) & 1)) >> 16;
  return (ushort)r;
}
static __device__ __forceinline__ unsigned pk2bf(float lo, float hi) {
  return (unsigned)f2bf(lo) | ((unsigned)f2bf(hi) << 16);
}

// ---- kernel 1: build BcT[b][o][128] bf16:  k<64 -> u[k][o], k>=64 -> W_x ----
// u = (me @ v_w^T + v_b) @ W_v^T ;  out_w = [W_x | W_v]
__global__ __launch_bounds__(256) void k_prep(
    const float* __restrict__ me, const float* __restrict__ vw,
    const float* __restrict__ vb, const float* __restrict__ ow,
    ushort* __restrict__ BcT) {
  __shared__ float A[64 * 132];
  __shared__ float W[64 * 132];
  __shared__ float VM[64 * 68];
  int b = blockIdx.x, t = threadIdx.x;
  for (int i = t; i < 8192; i += 256) {
    A[(i >> 7) * 132 + (i & 127)] = me[b * 8192 + i];
    W[(i >> 7) * 132 + (i & 127)] = vw[i];
  }
  __syncthreads();
  for (int idx = t; idx < 4096; idx += 256) {
    int a = idx >> 6, c = idx & 63;
    float acc = vb[c];
#pragma unroll 8
    for (int e = 0; e < 128; e += 4) {
      float4 x4 = *(const float4*)&A[a * 132 + e];
      float4 w4 = *(const float4*)&W[c * 132 + e];
      acc += x4.x * w4.x + x4.y * w4.y + x4.z * w4.z + x4.w * w4.w;
    }
    VM[a * 68 + c] = acc;
  }
  __syncthreads();
  for (int i = t; i < 8192; i += 256)
    W[(i >> 7) * 132 + (i & 127)] = ow[i];
  __syncthreads();
  for (int idx = t; idx < 4096; idx += 256) {
    int o = idx >> 6, a = idx & 63;
    float acc = 0.f;
#pragma unroll 8
    for (int c = 0; c < 64; c += 4) {
      float4 v4 = *(const float4*)&VM[a * 68 + c];
      float4 w4 = *(const float4*)&W[o * 132 + 64 + c];
      acc += v4.x * w4.x + v4.y * w4.y + v4.z * w4.z + v4.w * w4.w;
    }
    BcT[b * 8192 + o * 128 + a] = f2bf(acc);
  }
  for (int idx = t; idx < 4096; idx += 256) {
    int o = idx >> 6, ci = idx & 63;
    BcT[b * 8192 + o * 128 + 64 + ci] = f2bf(W[o * 132 + ci]);
  }
}

// --------- kernel 1b: conv weights -> bf16 [off][co][ci] ---------------------
__global__ void k_wt(const float* __restrict__ cw, ushort* __restrict__ wbf) {
  int idx = blockIdx.x * 256 + threadIdx.x;
  if (idx >= 27 * 64 * 64) return;
  int off = idx >> 12, r = idx & 4095, co = r >> 6, ci = r & 63;
  wbf[idx] = f2bf(cw[(co * 64 + ci) * 27 + off]);
}

// -------- kernel 2: softmax + fused [att|x] @ Bc MFMA -> h(bf16) -------------
// block = 128 voxels, 256 thr / 4 waves.  LDS 34 KB -> 4 blocks/CU.
__global__ __launch_bounds__(256) void k_att2(
    const float* __restrict__ x, const float* __restrict__ pos,
    const float* __restrict__ origin, const float* __restrict__ lattice,
    const int* __restrict__ bnodes, const float* __restrict__ ob,
    const ushort* __restrict__ BcT, ushort* __restrict__ hbf) {
  __shared__ __align__(16) char Ac[32768];   // [128 rows][256 B], slot^(row&7)
  __shared__ float ps[192];
  __shared__ float sinv[128];
  int t = threadIdx.x;
  int lane = t & 63, wave = t >> 6;
  int b = blockIdx.y;
  int v0 = blockIdx.x * 128;
  int lm = lane & 15, lg = lane >> 4;

  // B-fragments (registers, L2-hot): frag(kb,nt) lane -> BcT[o=nt*16+lm][kb*32+lg*8]
  short8 Bf[4][4];
  {
    const ushort* bp = BcT + b * 8192 + lm * 128 + lg * 8;
#pragma unroll
    for (int kb = 0; kb < 4; ++kb)
#pragma unroll
      for (int nt = 0; nt < 4; ++nt)
        Bf[kb][nt] = *(const short8*)(bp + nt * 2048 + kb * 32);
  }
  if (t < 192) ps[t] = pos[b * 192 + t];
  __syncthreads();

  // ---- e = exp(-dist) (unnormalized), bf16 -> Ac slots 0..7 ----
  {
    int v_loc = wave * 32 + (lane & 31);
    int half = lane >> 5;
    int v = v0 + v_loc;
    int ix = v / 2304;
    int rem = v - ix * 2304;
    int iy = rem / 48;
    int iz = rem - iy * 48;
    float gx = origin[b * 3 + 0] + lattice[b * 9 + 0] * (ix * (1.0f / 47.0f));
    float gy = origin[b * 3 + 1] + lattice[b * 9 + 4] * (iy * (1.0f / 47.0f));
    float gz = origin[b * 3 + 2] + lattice[b * 9 + 8] * (iz * (1.0f / 47.0f));
    int na = bnodes[b];
    int vswz = v_loc & 7;
    char* rowp = Ac + v_loc * 256;
    float s = 0.f;
#pragma unroll
    for (int i = 0; i < 32; i += 2) {
      float e2[2];
#pragma unroll
      for (int j = 0; j < 2; ++j) {
        int a = half * 32 + i + j;
        float dx = gx - ps[a * 3 + 0];
        float dy = gy - ps[a * 3 + 1];
        float dz = gz - ps[a * 3 + 2];
        float d = sqrtf(fmaxf(dx * dx + dy * dy + dz * dz, 1e-12f));
        float e = (a < na) ? __expf(-d) : 0.f;
        e2[j] = e;
        s += e;
      }
      int byteoff = (half * 32 + i) * 2;
      int slot = byteoff >> 4;
      *(unsigned*)(rowp + (((slot ^ vswz) << 4) | (byteoff & 15))) = pk2bf(e2[0], e2[1]);
    }
    s += __shfl_xor(s, 32);
    if (half == 0) sinv[v_loc] = 1.0f / s;
  }

  // ---- x -> bf16 -> Ac slots 8..15 (ci-pair packed uint writes) ----
  {
    int cp = t >> 3;   // ci = 2cp, 2cp+1
    int vq = t & 7;    // 16-voxel group
    const float* xa = x + ((size_t)(b * 64 + 2 * cp)) * NV + v0 + vq * 16;
    const float* xb2 = xa + NV;
    int slot = 8 + (cp >> 2);
    int off = (cp & 3) * 4;
#pragma unroll
    for (int it = 0; it < 4; ++it) {
      float4 fa = *(const float4*)(xa + it * 4);
      float4 fb = *(const float4*)(xb2 + it * 4);
      int rbase = vq * 16 + it * 4;
#pragma unroll
      for (int j = 0; j < 4; ++j) {
        int row = rbase + j;
        float va = ((const float*)&fa)[j];
        float vb2 = ((const float*)&fb)[j];
        *(unsigned*)(Ac + row * 256 + (((slot ^ (row & 7)) << 4) | off)) = pk2bf(va, vb2);
      }
    }
  }
  __syncthreads();

  // ---- MFMA: K 0..63 (att@u), scale by sinv, K 64..127 (x@W_x^T) ----
  f32x4 acc[2][4];
#pragma unroll
  for (int mt = 0; mt < 2; ++mt)
#pragma unroll
    for (int nt = 0; nt < 4; ++nt) acc[mt][nt] = (f32x4){0.f, 0.f, 0.f, 0.f};

  auto do_k = [&](int kb) {
    short8 Af[2];
#pragma unroll
    for (int mt = 0; mt < 2; ++mt) {
      int row = wave * 32 + mt * 16 + lm;
      Af[mt] = *(const short8*)(Ac + row * 256 + ((((kb << 2) + lg) ^ (row & 7)) << 4));
    }
#pragma unroll
    for (int mt = 0; mt < 2; ++mt)
#pragma unroll
      for (int nt = 0; nt < 4; ++nt)
        acc[mt][nt] = __builtin_amdgcn_mfma_f32_16x16x32_bf16(Af[mt], Bf[kb][nt], acc[mt][nt], 0, 0, 0);
  };
  do_k(0);
  do_k(1);
#pragma unroll
  for (int mt = 0; mt < 2; ++mt) {
    float4 s4 = *(const float4*)&sinv[wave * 32 + mt * 16 + lg * 4];
#pragma unroll
    for (int nt = 0; nt < 4; ++nt) {
      acc[mt][nt][0] *= s4.x;
      acc[mt][nt][1] *= s4.y;
      acc[mt][nt][2] *= s4.z;
      acc[mt][nt][3] *= s4.w;
    }
  }
  do_k(2);
  do_k(3);

  // ---- epilogue: relu(+ob) -> bf16 -> LDS [128][128B] swizzled -> global ----
  __syncthreads();
  float bo[4];
#pragma unroll
  for (int nt = 0; nt < 4; ++nt) bo[nt] = ob[nt * 16 + lm];
#pragma unroll
  for (int mt = 0; mt < 2; ++mt)
#pragma unroll
    for (int nt = 0; nt < 4; ++nt) {
      int o = nt * 16 + lm;
      int slot = o >> 3;
      int off = (o & 7) * 2;
#pragma unroll
      for (int r = 0; r < 4; ++r) {
        int row = wave * 32 + mt * 16 + lg * 4 + r;
        float hv = fmaxf(acc[mt][nt][r] + bo[nt], 0.f);
        *(ushort*)(Ac + row * 128 + (((slot ^ (row & 7)) << 4) | off)) = f2bf(hv);
      }
    }
  __syncthreads();
  char* dst = (char*)hbf + ((size_t)(b * NV + v0)) * 128;
#pragma unroll
  for (int k = 0; k < 4; ++k) {
    int i = t + k * 256;
    int row = i >> 3, s = i & 7;
    *(uint4*)(dst + row * 128 + s * 16) =
        *(const uint4*)(Ac + row * 128 + ((s ^ (row & 7)) << 4));
  }
}

// ------------- kernel 3: MFMA wrap-conv 3x3x3 + bias + relu + residual -------
__global__ __launch_bounds__(256) void k_conv(
    const ushort* __restrict__ hbf, const ushort* __restrict__ wbf,
    const float* __restrict__ cb, const float* __restrict__ x,
    float* __restrict__ out) {
  __shared__ char sm[71680];
  char* wb0 = sm + 55296;
  char* wb1 = sm + 63488;
  int t = threadIdx.x;
  int lane = t & 63, wave = t >> 6;
  int lm = lane & 15, lg = lane >> 4;

  int bid = blockIdx.x;
  int sw = (bid & 7) * 432 + (bid >> 3);
  int b = sw / 864, tid = sw - b * 864;
  int xt = tid / 36, rem = tid - xt * 36, yt = rem / 3, zt = rem - yt * 3;
  int x0 = xt * 2, y0 = yt * 4, z0 = zt * 16;

  const char* hbase = (const char*)hbf + (size_t)b * NV * 128;

  for (int c = t; c < 3456; c += 256) {
    int r = c >> 3, j = c & 7;
    int hx = r / 108, rr = r - hx * 108, hy = rr / 18, hz = rr - hy * 18;
    int gx = x0 + hx - 1; gx += (gx < 0) ? 48 : 0; gx -= (gx >= 48) ? 48 : 0;
    int gy = y0 + hy - 1; gy += (gy < 0) ? 48 : 0; gy -= (gy >= 48) ? 48 : 0;
    int gz = z0 + hz - 1; gz += (gz < 0) ? 48 : 0; gz -= (gz >= 48) ? 48 : 0;
    uint4 v = *(const uint4*)(hbase + ((size_t)(gx * 2304 + gy * 48 + gz) * 128 + j * 16));
    *(uint4*)(sm + r * 128 + ((j ^ (r & 7)) * 16)) = v;
  }
  {
    const char* ws = (const char*)wbf;
#pragma unroll
    for (int k = 0; k < 2; ++k) {
      int c = t + k * 256;
      int co = c >> 3, j = c & 7;
      uint4 v = *(const uint4*)(ws + c * 16);
      *(uint4*)(wb0 + co * 128 + ((j ^ (co & 7)) * 16)) = v;
    }
  }
  __syncthreads();

  f32x4 acc[2][4];
#pragma unroll
  for (int i = 0; i < 2; ++i)
#pragma unroll
    for (int j = 0; j < 4; ++j) acc[i][j] = (f32x4){0.f, 0.f, 0.f, 0.f};

  for (int off = 0; off < 27; ++off) {
    char* wcur = (off & 1) ? wb1 : wb0;
    char* wnxt = (off & 1) ? wb0 : wb1;
    uint4 wreg0, wreg1;
    bool pf = (off + 1 < 27);
    if (pf) {
      const char* ws = (const char*)wbf + (size_t)(off + 1) * 8192;
      wreg0 = *(const uint4*)(ws + t * 16);
      wreg1 = *(const uint4*)(ws + (t + 256) * 16);
    }
    int dx = off / 9, dyz = off - dx * 9, dy = dyz / 3, dz = dyz - dy * 3;
    int r_mt[2];
#pragma unroll
    for (int mt = 0; mt < 2; ++mt) {
      int q = wave * 2 + mt;
      int tx = q >> 2, ty = q & 3;
      r_mt[mt] = ((tx + dx) * 6 + (ty + dy)) * 18 + lm + dz;
    }
#pragma unroll
    for (int kc = 0; kc < 2; ++kc) {
      int s = kc * 4 + lg;
      short8 a[2], bb[4];
#pragma unroll
      for (int mt = 0; mt < 2; ++mt) {
        int r = r_mt[mt];
        a[mt] = *(const short8*)(sm + r * 128 + ((s ^ (r & 7)) * 16));
      }
#pragma unroll
      for (int nt = 0; nt < 4; ++nt) {
        int co = nt * 16 + lm;
        bb[nt] = *(const short8*)(wcur + co * 128 + ((s ^ (co & 7)) * 16));
      }
#pragma unroll
      for (int mt = 0; mt < 2; ++mt)
#pragma unroll
        for (int nt = 0; nt < 4; ++nt)
          acc[mt][nt] = __builtin_amdgcn_mfma_f32_16x16x32_bf16(a[mt], bb[nt], acc[mt][nt], 0, 0, 0);
    }
    if (pf) {
      int co0 = t >> 3, j0 = t & 7;
      *(uint4*)(wnxt + co0 * 128 + ((j0 ^ (co0 & 7)) * 16)) = wreg0;
      int c1 = t + 256, co1 = c1 >> 3, j1 = c1 & 7;
      *(uint4*)(wnxt + co1 * 128 + ((j1 ^ (co1 & 7)) * 16)) = wreg1;
    }
    __syncthreads();
  }

  float* ep = (float*)sm;
#pragma unroll
  for (int mt = 0; mt < 2; ++mt)
#pragma unroll
    for (int nt = 0; nt < 4; ++nt) {
      int co = nt * 16 + lm;
      int vbase = wave * 32 + mt * 16 + lg * 4;
#pragma unroll
      for (int rg = 0; rg < 4; ++rg)
        ep[co * 132 + vbase + rg] = acc[mt][nt][rg];
    }
  __syncthreads();
  const float* xb = x + (size_t)b * NC * NV;
  float* obp = out + (size_t)b * NC * NV;
  for (int i = t; i < 2048; i += 256) {
    int co = i >> 5, vq = i & 31;
    float4 v = *(const float4*)&ep[co * 132 + vq * 4];
    int vloc = vq * 4;
    int q = vloc >> 4, tz = vloc & 15;
    int tx = q >> 2, ty = q & 3;
    size_t g = (size_t)co * NV + (x0 + tx) * 2304 + (y0 + ty) * 48 + (z0 + tz);
    float4 xr = *(const float4*)(xb + g);
    float bias = cb[co];
    float4 o;
    o.x = fmaxf(v.x + bias, 0.f) + xr.x;
    o.y = fmaxf(v.y + bias, 0.f) + xr.y;
    o.z = fmaxf(v.z + bias, 0.f) + xr.z;
    o.w = fmaxf(v.w + bias, 0.f) + xr.w;
    *(float4*)(obp + g) = o;
  }
}

extern "C" void kernel_launch(void* const* d_in, const int* in_sizes, int n_in,
                              void* d_out, int out_size, void* d_ws, size_t ws_size,
                              hipStream_t stream) {
  const float* x = (const float*)d_in[0];
  const float* me = (const float*)d_in[1];
  const float* pos = (const float*)d_in[2];
  const float* origin = (const float*)d_in[3];
  const float* lattice = (const float*)d_in[4];
  const int* bn = (const int*)d_in[5];
  const float* vw = (const float*)d_in[6];
  const float* vb = (const float*)d_in[7];
  const float* ow = (const float*)d_in[8];
  const float* ob = (const float*)d_in[9];
  const float* cw = (const float*)d_in[10];
  const float* cbias = (const float*)d_in[11];
  float* outp = (float*)d_out;

  ushort* BcT = (ushort*)d_ws;                              // 64 KB
  ushort* wbf = (ushort*)((char*)d_ws + 65536);             // 216 KB
  ushort* hbf = (ushort*)((char*)d_ws + 65536 + 221184);    // 56.6 MB

  k_prep<<<NB, 256, 0, stream>>>(me, vw, vb, ow, BcT);
  k_wt<<<(27 * 64 * 64 + 255) / 256, 256, 0, stream>>>(cw, wbf);
  k_att2<<<dim3(NV / 128, NB), 256, 0, stream>>>(x, pos, origin, lattice, bn, ob, BcT, hbf);
  k_conv<<<3456, 256, 0, stream>>>(hbf, wbf, cbias, x, outp);
}